// Round 11
// baseline (298.872 us; speedup 1.0000x reference)
//
#include <hip/hip_runtime.h>
#include <hip/hip_bf16.h>
#include <math.h>
#include <stdint.h>

// ---------------------------------------------------------------------------
// DeepSetLayer / graph-attention fused pipeline.
// prep: MFMA q/k projection + nd->bf16, histogram(+u16 rank), Wc convert.
// CSR: scan + atomic-free scatter (u16 ids; requires N <= 65535).
// weights: wave/dst softmax -> wn[e] (no gather).
// agg: XCD-sliced gather (slice = blockIdx&7, 16 features/slice) -> att.
// final: bf16 MFMA GEMM + bias + row-L2-norm + relu (att aliases out).
// ---------------------------------------------------------------------------

#define IN_F 128
#define SMALL 12
#define QK_PAD 16
#define SCAN_ITEMS 8
#define SCAN_CHUNK 2048  // 256 threads * 8 items

typedef __attribute__((ext_vector_type(8))) short short8;   // 8 x bf16
typedef __attribute__((ext_vector_type(4))) float f32x4;

__device__ __forceinline__ unsigned short f2bf(float f) {
    union { float f; unsigned u; } v; v.f = f;
    unsigned r = v.u + 0x7fff + ((v.u >> 16) & 1);  // RNE
    return (unsigned short)(r >> 16);
}

__device__ __forceinline__ float2 bf2x2(unsigned v) {
    union { unsigned u; float f; } a, b;
    a.u = v << 16;
    b.u = v & 0xffff0000u;
    return make_float2(a.f, b.f);
}

__device__ __forceinline__ float dot12(const float* __restrict__ qrow,
                                       float4 c0, float4 c1, float4 c2) {
    float4 a = ((const float4*)qrow)[0];
    float4 b = ((const float4*)qrow)[1];
    float4 c = ((const float4*)qrow)[2];
    return a.x*c0.x + a.y*c0.y + a.z*c0.z + a.w*c0.w
         + b.x*c1.x + b.y*c1.y + b.z*c1.z + b.w*c1.w
         + c.x*c2.x + c.y*c2.y + c.z*c2.z + c.w*c2.w;
}

__device__ __forceinline__ short8 ld_bf8(const float* p) {
    float4 x0 = *(const float4*)p;
    float4 x1 = *(const float4*)(p + 4);
    short8 a;
    a[0] = (short)f2bf(x0.x); a[1] = (short)f2bf(x0.y);
    a[2] = (short)f2bf(x0.z); a[3] = (short)f2bf(x0.w);
    a[4] = (short)f2bf(x1.x); a[5] = (short)f2bf(x1.y);
    a[6] = (short)f2bf(x1.z); a[7] = (short)f2bf(x1.w);
    return a;
}

// ---- prep kernel (256 thr) -------------------------------------------------
__global__ __launch_bounds__(256) void prep_kernel(
    const float* __restrict__ nd,
    const float* __restrict__ Wq, const float* __restrict__ bq,
    const float* __restrict__ Wk, const float* __restrict__ bk,
    const int* __restrict__ dst,
    const float* __restrict__ W1, const float* __restrict__ W2,
    float* __restrict__ q, float* __restrict__ kf,
    unsigned short* __restrict__ ndb, int* __restrict__ cnt,
    unsigned short* __restrict__ rank, unsigned short* __restrict__ Wc,
    int N, int E, int NBQK, int NBCNT)
{
    int t = threadIdx.x;
    int b = blockIdx.x;

    if (b < NBQK) {
        // q|k projection via MFMA (16 nodes/wave) + ndb bf16 convert
        int wv = t >> 6;
        int lane = t & 63;
        int col = lane & 15;
        int quad = lane >> 4;
        int tbase = b * 64 + wv * 16;

        int arow = tbase + col;
        int rowc = (arow < N) ? arow : (N - 1);
        const float* ap = nd + (size_t)rowc * IN_F + quad * 8;
        unsigned short* np = ndb + (size_t)arow * IN_F + quad * 8;

        // B tile0 cols: [Wq rows 0..11 | Wk rows 0..3]; tile1: [Wk 4..11 | 0]
        const float* w0 = ((col < 12) ? (Wq + (size_t)col * IN_F)
                                      : (Wk + (size_t)(col - 12) * IN_F)) + quad * 8;
        const float* w1 = Wk + (size_t)((col < 8) ? (col + 4) : 4) * IN_F + quad * 8;
        bool hasw1 = (col < 8);

        f32x4 acc0 = (f32x4)0.f, acc1 = (f32x4)0.f;
#pragma unroll
        for (int ks = 0; ks < 4; ks++) {
            int k0 = ks * 32;
            short8 a = ld_bf8(ap + k0);
            if (arow < N) *(short8*)(np + k0) = a;
            short8 bb0 = ld_bf8(w0 + k0);
            short8 bb1 = hasw1 ? ld_bf8(w1 + k0) : (short8)0;
            acc0 = __builtin_amdgcn_mfma_f32_16x16x32_bf16(a, bb0, acc0, 0, 0, 0);
            acc1 = __builtin_amdgcn_mfma_f32_16x16x32_bf16(a, bb1, acc1, 0, 0, 0);
        }
        float bias0 = (col < 12) ? bq[col] : bk[col - 12];
        float bias1 = (col < 8) ? bk[col + 4] : 0.f;
#pragma unroll
        for (int r = 0; r < 4; r++) {
            int node = tbase + quad * 4 + r;
            if (node < N) {
                float v0 = acc0[r] + bias0;
                if (col < 12) q[(size_t)node * QK_PAD + col] = tanhf(v0);
                else          kf[(size_t)node * QK_PAD + (col - 12)] = v0;
                if (hasw1)    kf[(size_t)node * QK_PAD + col + 4] = acc1[r] + bias1;
            }
        }
    } else if (b < NBQK + NBCNT) {
        int ET = E + N;
        int stride = NBCNT * 256;
        for (int i = (b - NBQK) * 256 + t; i < ET; i += stride) {
            int d = (i < E) ? dst[i] : (i - E);
            rank[i] = (unsigned short)atomicAdd(&cnt[d], 1);
        }
    } else {
        int idx = (b - NBQK - NBCNT) * 256 + t;  // 0..32767
        int f = idx >> 8, k = idx & 255;
        float v = (k < 128) ? W1[f * 128 + k] : W2[f * 128 + (k - 128)];
        Wc[idx] = f2bf(v);
    }
}

// ---- scan phase 1 ----------------------------------------------------------
__global__ __launch_bounds__(256) void scan_local_kernel(
    int* __restrict__ off, int* __restrict__ bsum, int N)
{
    __shared__ int tsum[256];
    int t = threadIdx.x;
    int base = blockIdx.x * SCAN_CHUNK + t * SCAN_ITEMS;
    int v[SCAN_ITEMS];
    int s = 0;
#pragma unroll
    for (int i = 0; i < SCAN_ITEMS; i++) {
        int idx = base + i;
        v[i] = (idx < N) ? off[idx] : 0;
        s += v[i];
    }
    tsum[t] = s;
    __syncthreads();
    for (int d = 1; d < 256; d <<= 1) {
        int x = (t >= d) ? tsum[t - d] : 0;
        __syncthreads();
        tsum[t] += x;
        __syncthreads();
    }
    int excl = (t == 0) ? 0 : tsum[t - 1];
#pragma unroll
    for (int i = 0; i < SCAN_ITEMS; i++) {
        int idx = base + i;
        if (idx < N) off[idx] = excl;
        excl += v[i];
    }
    if (t == 255) bsum[blockIdx.x] = tsum[255];
}

// ---- scan phase 2 ----------------------------------------------------------
__global__ __launch_bounds__(256) void scan_add_kernel(
    int* __restrict__ off, const int* __restrict__ bsum, int N, int NB)
{
    __shared__ int pre2[2];
    int t = threadIdx.x;
    if (t == 0) {
        int p = 0, tot = 0;
        for (int i = 0; i < NB; i++) {
            int v = bsum[i];
            if (i < (int)blockIdx.x) p += v;
            tot += v;
        }
        pre2[0] = p; pre2[1] = tot;
    }
    __syncthreads();
    int add = pre2[0];
    if (blockIdx.x == 0 && t == 0) off[N] = pre2[1];

    int base = blockIdx.x * SCAN_CHUNK + t * SCAN_ITEMS;
#pragma unroll
    for (int i = 0; i < SCAN_ITEMS; i++) {
        int j = base + i;
        if (j < N) off[j] += add;
    }
}

// ---- scatter (atomic-free via rank, u16 ids) -------------------------------
__global__ __launch_bounds__(256) void scatter_kernel(
    const int* __restrict__ src, const int* __restrict__ dst,
    const int* __restrict__ off, const unsigned short* __restrict__ rank,
    unsigned short* __restrict__ esrc, int E, int N)
{
    int i = blockIdx.x * 256 + threadIdx.x;
    if (i >= E + N) return;
    int d, s;
    if (i < E) { d = dst[i]; s = src[i]; }
    else       { d = i - E; s = d; }
    esrc[off[d] + (int)rank[i]] = (unsigned short)s;
}

// ---- weights: wave per dst, softmax -> wn[e] (no row gather) ---------------
__global__ __launch_bounds__(256) void weights_kernel(
    const float* __restrict__ q, const float* __restrict__ kf,
    const int* __restrict__ off, const unsigned short* __restrict__ esrc,
    float* __restrict__ wn, int N)
{
    const float INVDK = 0.28867513459481287f;  // 1/sqrt(12)
    int wid = blockIdx.x * 4 + (threadIdx.x >> 6);
    if (wid >= N) return;
    int lane = threadIdx.x & 63;

    int start = off[wid];
    int deg = off[wid + 1] - start;

    const float4* kp = (const float4*)(kf + (size_t)wid * QK_PAD);
    float4 c0 = kp[0], c1 = kp[1], c2 = kp[2];

    if (deg <= 64) {
        float sc = -INFINITY;
        if (lane < deg) {
            int si = (int)esrc[start + lane];
            sc = dot12(q + (size_t)si * QK_PAD, c0, c1, c2) * INVDK;
        }
        float m = sc;
#pragma unroll
        for (int o = 32; o > 0; o >>= 1) m = fmaxf(m, __shfl_xor(m, o));
        float w = (lane < deg) ? __expf(sc - m) : 0.f;
        float lsum = w;
#pragma unroll
        for (int o = 32; o > 0; o >>= 1) lsum += __shfl_xor(lsum, o);
        float inv = 1.f / lsum;
        if (lane < deg) wn[start + lane] = w * inv;
    } else {
        float m = -INFINITY;
        for (int i = lane; i < deg; i += 64) {
            int s2 = (int)esrc[start + i];
            m = fmaxf(m, dot12(q + (size_t)s2 * QK_PAD, c0, c1, c2) * INVDK);
        }
#pragma unroll
        for (int o = 32; o > 0; o >>= 1) m = fmaxf(m, __shfl_xor(m, o));
        float lsum = 0.f;
        for (int i = lane; i < deg; i += 64) {
            int s2 = (int)esrc[start + i];
            lsum += __expf(dot12(q + (size_t)s2 * QK_PAD, c0, c1, c2) * INVDK - m);
        }
#pragma unroll
        for (int o = 32; o > 0; o >>= 1) lsum += __shfl_xor(lsum, o);
        float inv = 1.f / lsum;
        for (int i = lane; i < deg; i += 64) {
            int s2 = (int)esrc[start + i];
            wn[start + i] = __expf(dot12(q + (size_t)s2 * QK_PAD, c0, c1, c2) * INVDK - m) * inv;
        }
    }
}

// ---- agg: XCD-sliced weighted gather --------------------------------------
// slice = blockIdx & 7 (dispatch round-robin -> same slice stays on one XCD;
// heuristic for L2 residency, correctness-independent). Each slice covers 16
// features (32 B of a row): slice footprint ~3.2 MB incl. 64B-line sharing.
// Wave: 8 edge-groups x 8 feature-pair lanes; xor-shuffle reduce over groups.
__global__ __launch_bounds__(256) void agg_kernel(
    const unsigned short* __restrict__ ndb, const int* __restrict__ off,
    const unsigned short* __restrict__ esrc, const float* __restrict__ wn,
    float* __restrict__ att, int N, int NBB)
{
    int slice = blockIdx.x & 7;
    int bs = blockIdx.x >> 3;
    int wv = threadIdx.x >> 6;
    int lane = threadIdx.x & 63;
    int eg = lane >> 3;     // edge group 0..7
    int fp = lane & 7;      // feature pair 0..7
    int bcol = slice * 16 + fp * 2;

    for (int wid = bs * 4 + wv; wid < N; wid += NBB * 4) {
        int start = off[wid];
        int deg = off[wid + 1] - start;

        float ax = 0.f, ay = 0.f;
        int i = eg;
        // 2x unrolled: 2 independent gathers in flight per lane
        for (; i + 8 < deg; i += 16) {
            int e0 = start + i, e1 = start + i + 8;
            int r0 = (int)esrc[e0];
            int r1 = (int)esrc[e1];
            float w0 = wn[e0];
            float w1 = wn[e1];
            float2 f0 = bf2x2(*(const unsigned*)(ndb + (size_t)r0 * IN_F + bcol));
            float2 f1 = bf2x2(*(const unsigned*)(ndb + (size_t)r1 * IN_F + bcol));
            ax += w0 * f0.x + w1 * f1.x;
            ay += w0 * f0.y + w1 * f1.y;
        }
        if (i < deg) {
            int e0 = start + i;
            int r0 = (int)esrc[e0];
            float w0 = wn[e0];
            float2 f0 = bf2x2(*(const unsigned*)(ndb + (size_t)r0 * IN_F + bcol));
            ax += w0 * f0.x;
            ay += w0 * f0.y;
        }
        ax += __shfl_xor(ax, 8);  ay += __shfl_xor(ay, 8);
        ax += __shfl_xor(ax, 16); ay += __shfl_xor(ay, 16);
        ax += __shfl_xor(ax, 32); ay += __shfl_xor(ay, 32);
        if (eg == 0)
            *(float2*)(att + (size_t)wid * IN_F + bcol) = make_float2(ax, ay);
    }
}

// ---- final: out = relu(rownorm(nd@W1^T + att@W2^T + b2)), bf16 MFMA --------
__global__ __launch_bounds__(256) void final_kernel(
    const unsigned short* __restrict__ ndb, const float* __restrict__ nd,
    const float* __restrict__ att,
    const unsigned short* __restrict__ Wc, const float* __restrict__ b2,
    float* __restrict__ out, int N)
{
    int wv = threadIdx.x >> 6;
    int lane = threadIdx.x & 63;
    int col = lane & 15;
    int quad = lane >> 4;

    int arow = blockIdx.x * 64 + wv * 16 + col;
    int rowc = (arow < N) ? arow : (N - 1);
    const unsigned short* a0p = ndb + (size_t)rowc * IN_F + quad * 8;
    // OOB lanes read nd (never written) instead of att (aliases out)
    const float* a1p = ((arow < N) ? att : nd) + (size_t)rowc * IN_F + quad * 8;

    f32x4 acc[8];
#pragma unroll
    for (int i = 0; i < 8; i++) acc[i] = (f32x4)0.f;

#pragma unroll
    for (int ks = 0; ks < 8; ks++) {
        int k0 = ks * 32;
        short8 a;
        if (ks < 4) a = *(const short8*)(a0p + k0);
        else        a = ld_bf8(a1p + (k0 - 128));
#pragma unroll
        for (int ft = 0; ft < 8; ft++) {
            int n = ft * 16 + col;
            short8 bb = *(const short8*)(Wc + (size_t)n * 256 + k0 + quad * 8);
            acc[ft] = __builtin_amdgcn_mfma_f32_16x16x32_bf16(a, bb, acc[ft], 0, 0, 0);
        }
    }

    float bias[8];
#pragma unroll
    for (int ft = 0; ft < 8; ft++) bias[ft] = b2[ft * 16 + col];

#pragma unroll
    for (int r = 0; r < 4; r++) {
        int node = blockIdx.x * 64 + wv * 16 + quad * 4 + r;
        float v[8];
        float ps = 0.f;
#pragma unroll
        for (int ft = 0; ft < 8; ft++) {
            v[ft] = acc[ft][r] + bias[ft];
            ps += v[ft] * v[ft];
        }
        ps += __shfl_xor(ps, 1);
        ps += __shfl_xor(ps, 2);
        ps += __shfl_xor(ps, 4);
        ps += __shfl_xor(ps, 8);
        float rn = rsqrtf(ps);
        if (node < N) {
            float* op = out + (size_t)node * 128 + col;
#pragma unroll
            for (int ft = 0; ft < 8; ft++)
                op[ft * 16] = fmaxf(v[ft] * rn, 0.f);
        }
    }
}

// ---------------------------------------------------------------------------
static inline char* align_up(char* p, size_t a) {
    return (char*)(((uintptr_t)p + (a - 1)) & ~(uintptr_t)(a - 1));
}

extern "C" void kernel_launch(void* const* d_in, const int* in_sizes, int n_in,
                              void* d_out, int out_size, void* d_ws, size_t ws_size,
                              hipStream_t stream) {
    const float* node_data = (const float*)d_in[0];
    const int*   src       = (const int*)d_in[1];
    const int*   dst       = (const int*)d_in[2];
    const float* Wq        = (const float*)d_in[3];
    const float* bq        = (const float*)d_in[4];
    const float* Wk        = (const float*)d_in[5];
    const float* bk        = (const float*)d_in[6];
    const float* W1        = (const float*)d_in[7];
    const float* W2        = (const float*)d_in[8];
    const float* b2        = (const float*)d_in[9];
    float* out = (float*)d_out;

    int N = in_sizes[0] / IN_F;
    int E = in_sizes[1];
    int ET = E + N;
    int NB = (N + SCAN_CHUNK - 1) / SCAN_CHUNK;   // 25
    int NBQK = (N + 63) / 64;                      // 782
    int NBCNT = 512;
    int NBCVT = 128;
    int NBB = (N + 31) / 32;                       // agg blocks per slice (4 waves, ~8 dst/wave)

    char* w = (char*)d_ws;
    float* q  = (float*)w;  w += (size_t)N * QK_PAD * sizeof(float);
    float* kf = (float*)w;  w += (size_t)N * QK_PAD * sizeof(float);
    w = align_up(w, 256);
    unsigned short* ndb = (unsigned short*)w;  w += (size_t)N * IN_F * sizeof(unsigned short);
    w = align_up(w, 256);
    unsigned short* Wc = (unsigned short*)w;  w += 128 * 256 * sizeof(unsigned short);
    int* off  = (int*)w;  w += (size_t)(N + 1) * sizeof(int);
    int* bsum = (int*)w;  w += 256 * sizeof(int);
    float* wn = (float*)w;  w += (size_t)ET * sizeof(float);
    unsigned short* rank = (unsigned short*)w;  w += (size_t)ET * sizeof(unsigned short);
    w = align_up(w, 256);
    unsigned short* esrc = (unsigned short*)w;  w += (size_t)ET * sizeof(unsigned short);
    float* att = out;  // att aliases d_out (final is tile-local)

    hipMemsetAsync(off, 0, (size_t)(N + 1) * sizeof(int), stream);

    prep_kernel<<<NBQK + NBCNT + NBCVT, 256, 0, stream>>>(
        node_data, Wq, bq, Wk, bk, dst, W1, W2,
        q, kf, ndb, off, rank, Wc, N, E, NBQK, NBCNT);
    scan_local_kernel<<<NB, 256, 0, stream>>>(off, bsum, N);
    scan_add_kernel<<<NB, 256, 0, stream>>>(off, bsum, N, NB);
    scatter_kernel<<<(ET + 255) / 256, 256, 0, stream>>>(src, dst, off, rank, esrc, E, N);
    weights_kernel<<<(N + 3) / 4, 256, 0, stream>>>(q, kf, off, esrc, wn, N);
    agg_kernel<<<NBB * 8, 256, 0, stream>>>(ndb, off, esrc, wn, att, N, NBB);
    final_kernel<<<(N + 63) / 64, 256, 0, stream>>>(ndb, node_data, att, Wc, b2, out, N);
}

// Round 12
// 220.474 us; speedup vs baseline: 1.3556x; 1.3556x over previous
//
#include <hip/hip_runtime.h>
#include <hip/hip_bf16.h>
#include <math.h>
#include <stdint.h>

// ---------------------------------------------------------------------------
// DeepSetLayer / graph-attention fused pipeline.
// prep: MFMA q/k projection + nd->bf16, histogram(+u16 rank), Wc convert.
// CSR: scan + atomic-free scatter (u16 ids; requires N <= 65535).
// attn: 16-lane group per dst; softmax fp32; gather = uint4 (16B/lane) of
//       bf16 rows, 4 groups/wave, 4x unrolled -> ~16 loads in flight/wave.
// final: bf16 MFMA GEMM + bias + row-L2-norm + relu (att aliases out).
// ---------------------------------------------------------------------------

#define IN_F 128
#define SMALL 12
#define QK_PAD 16
#define SCAN_ITEMS 8
#define SCAN_CHUNK 2048  // 256 threads * 8 items

typedef __attribute__((ext_vector_type(8))) short short8;   // 8 x bf16
typedef __attribute__((ext_vector_type(4))) float f32x4;

__device__ __forceinline__ unsigned short f2bf(float f) {
    union { float f; unsigned u; } v; v.f = f;
    unsigned r = v.u + 0x7fff + ((v.u >> 16) & 1);  // RNE
    return (unsigned short)(r >> 16);
}

__device__ __forceinline__ float2 bf2x2(unsigned v) {
    union { unsigned u; float f; } a, b;
    a.u = v << 16;
    b.u = v & 0xffff0000u;
    return make_float2(a.f, b.f);
}

__device__ __forceinline__ float dot12(const float* __restrict__ qrow,
                                       float4 c0, float4 c1, float4 c2) {
    float4 a = ((const float4*)qrow)[0];
    float4 b = ((const float4*)qrow)[1];
    float4 c = ((const float4*)qrow)[2];
    return a.x*c0.x + a.y*c0.y + a.z*c0.z + a.w*c0.w
         + b.x*c1.x + b.y*c1.y + b.z*c1.z + b.w*c1.w
         + c.x*c2.x + c.y*c2.y + c.z*c2.z + c.w*c2.w;
}

__device__ __forceinline__ short8 ld_bf8(const float* p) {
    float4 x0 = *(const float4*)p;
    float4 x1 = *(const float4*)(p + 4);
    short8 a;
    a[0] = (short)f2bf(x0.x); a[1] = (short)f2bf(x0.y);
    a[2] = (short)f2bf(x0.z); a[3] = (short)f2bf(x0.w);
    a[4] = (short)f2bf(x1.x); a[5] = (short)f2bf(x1.y);
    a[6] = (short)f2bf(x1.z); a[7] = (short)f2bf(x1.w);
    return a;
}

// ---- prep kernel (256 thr) -------------------------------------------------
__global__ __launch_bounds__(256) void prep_kernel(
    const float* __restrict__ nd,
    const float* __restrict__ Wq, const float* __restrict__ bq,
    const float* __restrict__ Wk, const float* __restrict__ bk,
    const int* __restrict__ dst,
    const float* __restrict__ W1, const float* __restrict__ W2,
    float* __restrict__ q, float* __restrict__ kf,
    unsigned short* __restrict__ ndb, int* __restrict__ cnt,
    unsigned short* __restrict__ rank, unsigned short* __restrict__ Wc,
    int N, int E, int NBQK, int NBCNT)
{
    int t = threadIdx.x;
    int b = blockIdx.x;

    if (b < NBQK) {
        // q|k projection via MFMA (16 nodes/wave) + ndb bf16 convert
        int wv = t >> 6;
        int lane = t & 63;
        int col = lane & 15;
        int quad = lane >> 4;
        int tbase = b * 64 + wv * 16;

        int arow = tbase + col;
        int rowc = (arow < N) ? arow : (N - 1);
        const float* ap = nd + (size_t)rowc * IN_F + quad * 8;
        unsigned short* np = ndb + (size_t)arow * IN_F + quad * 8;

        // B tile0 cols: [Wq rows 0..11 | Wk rows 0..3]; tile1: [Wk 4..11 | 0]
        const float* w0 = ((col < 12) ? (Wq + (size_t)col * IN_F)
                                      : (Wk + (size_t)(col - 12) * IN_F)) + quad * 8;
        const float* w1 = Wk + (size_t)((col < 8) ? (col + 4) : 4) * IN_F + quad * 8;
        bool hasw1 = (col < 8);

        f32x4 acc0 = (f32x4)0.f, acc1 = (f32x4)0.f;
#pragma unroll
        for (int ks = 0; ks < 4; ks++) {
            int k0 = ks * 32;
            short8 a = ld_bf8(ap + k0);
            if (arow < N) *(short8*)(np + k0) = a;
            short8 bb0 = ld_bf8(w0 + k0);
            short8 bb1 = hasw1 ? ld_bf8(w1 + k0) : (short8)0;
            acc0 = __builtin_amdgcn_mfma_f32_16x16x32_bf16(a, bb0, acc0, 0, 0, 0);
            acc1 = __builtin_amdgcn_mfma_f32_16x16x32_bf16(a, bb1, acc1, 0, 0, 0);
        }
        float bias0 = (col < 12) ? bq[col] : bk[col - 12];
        float bias1 = (col < 8) ? bk[col + 4] : 0.f;
#pragma unroll
        for (int r = 0; r < 4; r++) {
            int node = tbase + quad * 4 + r;
            if (node < N) {
                float v0 = acc0[r] + bias0;
                if (col < 12) q[(size_t)node * QK_PAD + col] = tanhf(v0);
                else          kf[(size_t)node * QK_PAD + (col - 12)] = v0;
                if (hasw1)    kf[(size_t)node * QK_PAD + col + 4] = acc1[r] + bias1;
            }
        }
    } else if (b < NBQK + NBCNT) {
        int ET = E + N;
        int stride = NBCNT * 256;
        for (int i = (b - NBQK) * 256 + t; i < ET; i += stride) {
            int d = (i < E) ? dst[i] : (i - E);
            rank[i] = (unsigned short)atomicAdd(&cnt[d], 1);
        }
    } else {
        int idx = (b - NBQK - NBCNT) * 256 + t;  // 0..32767
        int f = idx >> 8, k = idx & 255;
        float v = (k < 128) ? W1[f * 128 + k] : W2[f * 128 + (k - 128)];
        Wc[idx] = f2bf(v);
    }
}

// ---- scan phase 1 ----------------------------------------------------------
__global__ __launch_bounds__(256) void scan_local_kernel(
    int* __restrict__ off, int* __restrict__ bsum, int N)
{
    __shared__ int tsum[256];
    int t = threadIdx.x;
    int base = blockIdx.x * SCAN_CHUNK + t * SCAN_ITEMS;
    int v[SCAN_ITEMS];
    int s = 0;
#pragma unroll
    for (int i = 0; i < SCAN_ITEMS; i++) {
        int idx = base + i;
        v[i] = (idx < N) ? off[idx] : 0;
        s += v[i];
    }
    tsum[t] = s;
    __syncthreads();
    for (int d = 1; d < 256; d <<= 1) {
        int x = (t >= d) ? tsum[t - d] : 0;
        __syncthreads();
        tsum[t] += x;
        __syncthreads();
    }
    int excl = (t == 0) ? 0 : tsum[t - 1];
#pragma unroll
    for (int i = 0; i < SCAN_ITEMS; i++) {
        int idx = base + i;
        if (idx < N) off[idx] = excl;
        excl += v[i];
    }
    if (t == 255) bsum[blockIdx.x] = tsum[255];
}

// ---- scan phase 2 ----------------------------------------------------------
__global__ __launch_bounds__(256) void scan_add_kernel(
    int* __restrict__ off, const int* __restrict__ bsum, int N, int NB)
{
    __shared__ int pre2[2];
    int t = threadIdx.x;
    if (t == 0) {
        int p = 0, tot = 0;
        for (int i = 0; i < NB; i++) {
            int v = bsum[i];
            if (i < (int)blockIdx.x) p += v;
            tot += v;
        }
        pre2[0] = p; pre2[1] = tot;
    }
    __syncthreads();
    int add = pre2[0];
    if (blockIdx.x == 0 && t == 0) off[N] = pre2[1];

    int base = blockIdx.x * SCAN_CHUNK + t * SCAN_ITEMS;
#pragma unroll
    for (int i = 0; i < SCAN_ITEMS; i++) {
        int j = base + i;
        if (j < N) off[j] += add;
    }
}

// ---- scatter (atomic-free via rank, u16 ids) -------------------------------
__global__ __launch_bounds__(256) void scatter_kernel(
    const int* __restrict__ src, const int* __restrict__ dst,
    const int* __restrict__ off, const unsigned short* __restrict__ rank,
    unsigned short* __restrict__ esrc, int E, int N)
{
    int i = blockIdx.x * 256 + threadIdx.x;
    if (i >= E + N) return;
    int d, s;
    if (i < E) { d = dst[i]; s = src[i]; }
    else       { d = i - E; s = d; }
    esrc[off[d] + (int)rank[i]] = (unsigned short)s;
}

// ---- attn: 16-lane group per dst -------------------------------------------
// Group gathers full 256B bf16 rows as uint4 per lane (features l16*8..+7).
// Softmax fp32 in 16-lane shuffles. 4 dsts per wave; gather 4x unrolled.
__global__ __launch_bounds__(256) void attn_kernel(
    const unsigned short* __restrict__ ndb, const float* __restrict__ q,
    const float* __restrict__ kf, const int* __restrict__ off,
    const unsigned short* __restrict__ esrc, float* __restrict__ att, int N)
{
    const float INVDK = 0.28867513459481287f;  // 1/sqrt(12)
    int t = threadIdx.x;
    int lane = t & 63;
    int l16 = lane & 15;
    int gbase = lane & 48;          // group base lane within wave
    int wid = blockIdx.x * 16 + (t >> 4);
    if (wid >= N) return;

    int start = off[wid];
    int deg = off[wid + 1] - start;

    const float4* kp = (const float4*)(kf + (size_t)wid * QK_PAD);
    float4 c0 = kp[0], c1 = kp[1], c2 = kp[2];

    float acc[8];
#pragma unroll
    for (int j = 0; j < 8; j++) acc[j] = 0.f;
    float inv;

    const unsigned short* nb = ndb + l16 * 8;

#define ACCUM(vv, ww) do {                                                    \
        float2 f0 = bf2x2((vv).x), f1 = bf2x2((vv).y);                        \
        float2 f2 = bf2x2((vv).z), f3 = bf2x2((vv).w);                        \
        acc[0] += (ww) * f0.x; acc[1] += (ww) * f0.y;                         \
        acc[2] += (ww) * f1.x; acc[3] += (ww) * f1.y;                         \
        acc[4] += (ww) * f2.x; acc[5] += (ww) * f2.y;                         \
        acc[6] += (ww) * f3.x; acc[7] += (ww) * f3.y;                         \
    } while (0)

    if (deg <= 16) {
        float sc = -INFINITY;
        int si = 0;
        if (l16 < deg) {
            si = (int)esrc[start + l16];
            sc = dot12(q + (size_t)si * QK_PAD, c0, c1, c2) * INVDK;
        }
        float m = sc;
#pragma unroll
        for (int o = 8; o > 0; o >>= 1) m = fmaxf(m, __shfl_xor(m, o));
        float w = (l16 < deg) ? __expf(sc - m) : 0.f;
        float ls = w;
#pragma unroll
        for (int o = 8; o > 0; o >>= 1) ls += __shfl_xor(ls, o);
        inv = 1.f / ls;

        int i = 0;
        for (; i + 4 <= deg; i += 4) {
            float w0 = __shfl(w, gbase | i);       int r0 = __shfl(si, gbase | i);
            float w1 = __shfl(w, gbase | (i + 1)); int r1 = __shfl(si, gbase | (i + 1));
            float w2 = __shfl(w, gbase | (i + 2)); int r2 = __shfl(si, gbase | (i + 2));
            float w3 = __shfl(w, gbase | (i + 3)); int r3 = __shfl(si, gbase | (i + 3));
            uint4 v0 = *(const uint4*)(nb + (size_t)r0 * IN_F);
            uint4 v1 = *(const uint4*)(nb + (size_t)r1 * IN_F);
            uint4 v2 = *(const uint4*)(nb + (size_t)r2 * IN_F);
            uint4 v3 = *(const uint4*)(nb + (size_t)r3 * IN_F);
            ACCUM(v0, w0); ACCUM(v1, w1); ACCUM(v2, w2); ACCUM(v3, w3);
        }
        for (; i < deg; i++) {
            float wi = __shfl(w, gbase | i);
            int ri = __shfl(si, gbase | i);
            uint4 v = *(const uint4*)(nb + (size_t)ri * IN_F);
            ACCUM(v, wi);
        }
    } else {
        // chunked (deg > 16): recompute scores per pass
        float m = -INFINITY;
        for (int i = l16; i < deg; i += 16) {
            int s2 = (int)esrc[start + i];
            m = fmaxf(m, dot12(q + (size_t)s2 * QK_PAD, c0, c1, c2) * INVDK);
        }
#pragma unroll
        for (int o = 8; o > 0; o >>= 1) m = fmaxf(m, __shfl_xor(m, o));
        float ls = 0.f;
        for (int i = l16; i < deg; i += 16) {
            int s2 = (int)esrc[start + i];
            ls += __expf(dot12(q + (size_t)s2 * QK_PAD, c0, c1, c2) * INVDK - m);
        }
#pragma unroll
        for (int o = 8; o > 0; o >>= 1) ls += __shfl_xor(ls, o);
        inv = 1.f / ls;

        for (int base2 = 0; base2 < deg; base2 += 16) {
            int cnt2 = deg - base2; if (cnt2 > 16) cnt2 = 16;
            float w = 0.f; int si = 0;
            if (l16 < cnt2) {
                si = (int)esrc[start + base2 + l16];
                w = __expf(dot12(q + (size_t)si * QK_PAD, c0, c1, c2) * INVDK - m);
            }
            int i = 0;
            for (; i + 4 <= cnt2; i += 4) {
                float w0 = __shfl(w, gbase | i);       int r0 = __shfl(si, gbase | i);
                float w1 = __shfl(w, gbase | (i + 1)); int r1 = __shfl(si, gbase | (i + 1));
                float w2 = __shfl(w, gbase | (i + 2)); int r2 = __shfl(si, gbase | (i + 2));
                float w3 = __shfl(w, gbase | (i + 3)); int r3 = __shfl(si, gbase | (i + 3));
                uint4 v0 = *(const uint4*)(nb + (size_t)r0 * IN_F);
                uint4 v1 = *(const uint4*)(nb + (size_t)r1 * IN_F);
                uint4 v2 = *(const uint4*)(nb + (size_t)r2 * IN_F);
                uint4 v3 = *(const uint4*)(nb + (size_t)r3 * IN_F);
                ACCUM(v0, w0); ACCUM(v1, w1); ACCUM(v2, w2); ACCUM(v3, w3);
            }
            for (; i < cnt2; i++) {
                float wi = __shfl(w, gbase | i);
                int ri = __shfl(si, gbase | i);
                uint4 v = *(const uint4*)(nb + (size_t)ri * IN_F);
                ACCUM(v, wi);
            }
        }
    }
#undef ACCUM

    float* op = att + (size_t)wid * IN_F + l16 * 8;
    float4 s0, s1;
    s0.x = acc[0] * inv; s0.y = acc[1] * inv; s0.z = acc[2] * inv; s0.w = acc[3] * inv;
    s1.x = acc[4] * inv; s1.y = acc[5] * inv; s1.z = acc[6] * inv; s1.w = acc[7] * inv;
    *(float4*)op = s0;
    *(float4*)(op + 4) = s1;
}

// ---- final: out = relu(rownorm(nd@W1^T + att@W2^T + b2)), bf16 MFMA --------
__global__ __launch_bounds__(256) void final_kernel(
    const unsigned short* __restrict__ ndb, const float* __restrict__ nd,
    const float* __restrict__ att,
    const unsigned short* __restrict__ Wc, const float* __restrict__ b2,
    float* __restrict__ out, int N)
{
    int wv = threadIdx.x >> 6;
    int lane = threadIdx.x & 63;
    int col = lane & 15;
    int quad = lane >> 4;

    int arow = blockIdx.x * 64 + wv * 16 + col;
    int rowc = (arow < N) ? arow : (N - 1);
    const unsigned short* a0p = ndb + (size_t)rowc * IN_F + quad * 8;
    // OOB lanes read nd (never written) instead of att (aliases out)
    const float* a1p = ((arow < N) ? att : nd) + (size_t)rowc * IN_F + quad * 8;

    f32x4 acc[8];
#pragma unroll
    for (int i = 0; i < 8; i++) acc[i] = (f32x4)0.f;

#pragma unroll
    for (int ks = 0; ks < 8; ks++) {
        int k0 = ks * 32;
        short8 a;
        if (ks < 4) a = *(const short8*)(a0p + k0);
        else        a = ld_bf8(a1p + (k0 - 128));
#pragma unroll
        for (int ft = 0; ft < 8; ft++) {
            int n = ft * 16 + col;
            short8 bb = *(const short8*)(Wc + (size_t)n * 256 + k0 + quad * 8);
            acc[ft] = __builtin_amdgcn_mfma_f32_16x16x32_bf16(a, bb, acc[ft], 0, 0, 0);
        }
    }

    float bias[8];
#pragma unroll
    for (int ft = 0; ft < 8; ft++) bias[ft] = b2[ft * 16 + col];

#pragma unroll
    for (int r = 0; r < 4; r++) {
        int node = blockIdx.x * 64 + wv * 16 + quad * 4 + r;
        float v[8];
        float ps = 0.f;
#pragma unroll
        for (int ft = 0; ft < 8; ft++) {
            v[ft] = acc[ft][r] + bias[ft];
            ps += v[ft] * v[ft];
        }
        ps += __shfl_xor(ps, 1);
        ps += __shfl_xor(ps, 2);
        ps += __shfl_xor(ps, 4);
        ps += __shfl_xor(ps, 8);
        float rn = rsqrtf(ps);
        if (node < N) {
            float* op = out + (size_t)node * 128 + col;
#pragma unroll
            for (int ft = 0; ft < 8; ft++)
                op[ft * 16] = fmaxf(v[ft] * rn, 0.f);
        }
    }
}

// ---------------------------------------------------------------------------
static inline char* align_up(char* p, size_t a) {
    return (char*)(((uintptr_t)p + (a - 1)) & ~(uintptr_t)(a - 1));
}

extern "C" void kernel_launch(void* const* d_in, const int* in_sizes, int n_in,
                              void* d_out, int out_size, void* d_ws, size_t ws_size,
                              hipStream_t stream) {
    const float* node_data = (const float*)d_in[0];
    const int*   src       = (const int*)d_in[1];
    const int*   dst       = (const int*)d_in[2];
    const float* Wq        = (const float*)d_in[3];
    const float* bq        = (const float*)d_in[4];
    const float* Wk        = (const float*)d_in[5];
    const float* bk        = (const float*)d_in[6];
    const float* W1        = (const float*)d_in[7];
    const float* W2        = (const float*)d_in[8];
    const float* b2        = (const float*)d_in[9];
    float* out = (float*)d_out;

    int N = in_sizes[0] / IN_F;
    int E = in_sizes[1];
    int ET = E + N;
    int NB = (N + SCAN_CHUNK - 1) / SCAN_CHUNK;   // 25
    int NBQK = (N + 63) / 64;                      // 782
    int NBCNT = 512;
    int NBCVT = 128;

    char* w = (char*)d_ws;
    float* q  = (float*)w;  w += (size_t)N * QK_PAD * sizeof(float);
    float* kf = (float*)w;  w += (size_t)N * QK_PAD * sizeof(float);
    w = align_up(w, 256);
    unsigned short* ndb = (unsigned short*)w;  w += (size_t)N * IN_F * sizeof(unsigned short);
    w = align_up(w, 256);
    unsigned short* Wc = (unsigned short*)w;  w += 128 * 256 * sizeof(unsigned short);
    int* off  = (int*)w;  w += (size_t)(N + 1) * sizeof(int);
    int* bsum = (int*)w;  w += 256 * sizeof(int);
    unsigned short* rank = (unsigned short*)w;  w += (size_t)ET * sizeof(unsigned short);
    w = align_up(w, 256);
    unsigned short* esrc = (unsigned short*)w;  w += (size_t)ET * sizeof(unsigned short);
    float* att = out;  // att aliases d_out (final is tile-local)

    hipMemsetAsync(off, 0, (size_t)(N + 1) * sizeof(int), stream);

    prep_kernel<<<NBQK + NBCNT + NBCVT, 256, 0, stream>>>(
        node_data, Wq, bq, Wk, bk, dst, W1, W2,
        q, kf, ndb, off, rank, Wc, N, E, NBQK, NBCNT);
    scan_local_kernel<<<NB, 256, 0, stream>>>(off, bsum, N);
    scan_add_kernel<<<NB, 256, 0, stream>>>(off, bsum, N, NB);
    scatter_kernel<<<(ET + 255) / 256, 256, 0, stream>>>(src, dst, off, rank, esrc, E, N);
    attn_kernel<<<(N + 15) / 16, 256, 0, stream>>>(ndb, q, kf, off, esrc, att, N);
    final_kernel<<<(N + 63) / 64, 256, 0, stream>>>(ndb, node_data, att, Wc, b2, out, N);
}